// Round 5
// baseline (5861.324 us; speedup 1.0000x reference)
//
#include <hip/hip_runtime.h>
#include <hip/hip_bf16.h>
#include <cstdint>

typedef __bf16 bf16_t;
typedef __bf16 bf16x4 __attribute__((ext_vector_type(4)));
typedef __bf16 bf16x8 __attribute__((ext_vector_type(8)));
typedef float f32x4 __attribute__((ext_vector_type(4)));

#define BATCH 4096
#define DIN   1024
#define HID   2048
#define DOUT  1000
#define NITER 50
#define LR    0.001f

#define BM 128
#define BN 128
#define BK 32
#define NBUF 3

// async global -> LDS, 16 B per lane. LDS dest is wave-uniform base + lane*16.
#define GLDS(g, l)                                                        \
    __builtin_amdgcn_global_load_lds(                                     \
        (const __attribute__((address_space(1))) void*)(g),               \
        (__attribute__((address_space(3))) void*)(l), 16, 0, 0)

#define WAITVM(N) asm volatile("s_waitcnt vmcnt(" #N ")" ::: "memory")
#define BAR()     __builtin_amdgcn_s_barrier()
#define SCHEDB()  __builtin_amdgcn_sched_barrier(0)

// ---------------------------------------------------------------------------
// gemm_bt: C[M,N] = A[M,K] @ Bt[N,K]^T, row-major, bf16 in, f32 acc.
// 256 threads = 4 waves (2x2); wave tile 64x64 -> acc[4][4] (m97 shape:
// 8 ds_read_b128 per 16 MFMA = 32 FLOP/LDS-byte).
// K-loop: triple-buffered LDS, depth-3 pipeline, COUNTED vmcnt (T4):
// vmcnt(8) steady (2 tiles in flight across barriers), 8->4->0 tail.
// T2 swizzle: LDS read idx ^= ((row&7)<<3)  (byte ^= ((row&7)<<4)), which
// spreads the 64B-row-stride fragment reads across 8 bank-starts (2-way =
// free).  global_load_lds writes LINEARLY, so the per-lane GLOBAL source is
// pre-inverse-swizzled (rule #21 / m173 pattern):
//   linear dest byte q (= lane*16): logical row bit0 = q6^q8, col chunk
//   c1 = q5^q7, c0 = q4^q6^q8.
// EPI: 2  = h-update (B1 = W_rec)
//      3  = y-update (B1 = W_out padded)
//      13 = merged: blockIdx.y<8 -> role 3 (B2=W_out), else role 1 (B1=W_rec^T)
// ---------------------------------------------------------------------------
template <int EPI>
__global__ __launch_bounds__(256) void gemm_bt(
    const bf16_t* __restrict__ A, const bf16_t* __restrict__ B1,
    const bf16_t* __restrict__ B2, int K,
    const float* __restrict__ xin, const float* __restrict__ bias_g,
    const float* __restrict__ bias_o,
    bf16_t* __restrict__ exout, float* __restrict__ hf, bf16_t* __restrict__ hb,
    float* __restrict__ yout, float* __restrict__ energy)
{
    __shared__ __align__(16) bf16_t sA[NBUF][BM * BK];
    __shared__ __align__(16) bf16_t sB[NBUF][BN * BK];
    __shared__ float red[4];

    const int t    = threadIdx.x;
    const int lane = t & 63;
    const int wave = t >> 6;        // 0..3
    const int wm   = wave >> 1;     // wave row (0..1) -> 64 rows
    const int wn   = wave & 1;      // wave col (0..1) -> 64 cols
    const int m0   = blockIdx.x * BM;
    const int lr   = lane & 15;        // fragment row/col within 16
    const int lkb  = (lane >> 4) * 8;  // fragment k chunk (8 contiguous bf16)
    const int sw   = (lr & 7) << 3;    // T2 read-side swizzle (elem units)

    int role = EPI;
    int n0   = blockIdx.y * BN;
    const bf16_t* Bt = B1;
    if constexpr (EPI == 13) {
        if ((int)blockIdx.y < 8) {            // role 3: W_out cols 0..1023
            role = 3; Bt = B2;
        } else {                              // role 1: W_rec^T cols 0..1023
            role = 1; Bt = B1; n0 = ((int)blockIdx.y - 8) * BN;
        }
    }

    f32x4 acc[4][4] = {};

    // --- staging source: inverse-swizzled per-lane global address ----------
    // linear LDS dest byte for lane l (within a 1KB chunk) = l*16:
    //   q4=l0 q5=l1 q6=l2 q7=l3 q8=l4 q9=l5
    // logical row-in-chunk rr and col chunk cc:
    const int l0 = lane & 1, l1 = (lane >> 1) & 1, l2 = (lane >> 2) & 1;
    const int l3 = (lane >> 3) & 1, l4 = (lane >> 4) & 1, l5 = (lane >> 5) & 1;
    const int rr = (l5 << 3) | (l4 << 2) | (l3 << 1) | (l2 ^ l4);
    const int cc = ((l1 ^ l3) << 1) | (l0 ^ l2 ^ l4);
    // wave w stages tile rows [w*32, w*32+32): chunk0 rows +0..15, chunk1 +16..31
    const bf16_t* gA = A  + (int64_t)(m0 + wave * 32 + rr) * K + cc * 8;
    const bf16_t* gB = Bt + (int64_t)(n0 + wave * 32 + rr) * K + cc * 8;

    auto stage = [&](int tile, int buf) {
        const int64_t ko = (int64_t)tile * BK;
        GLDS(gA + ko,                    &sA[buf][wave * 1024]);
        GLDS(gA + ko + (int64_t)16 * K,  &sA[buf][wave * 1024 + 512]);
        GLDS(gB + ko,                    &sB[buf][wave * 1024]);
        GLDS(gB + ko + (int64_t)16 * K,  &sB[buf][wave * 1024 + 512]);
    };

    auto compute = [&](int buf) {
        bf16x8 af[4], bfr[4];
#pragma unroll
        for (int mi = 0; mi < 4; ++mi)
            af[mi] = *reinterpret_cast<const bf16x8*>(
                &sA[buf][((wm * 64 + mi * 16 + lr) * BK + lkb) ^ sw]);
#pragma unroll
        for (int ni = 0; ni < 4; ++ni)
            bfr[ni] = *reinterpret_cast<const bf16x8*>(
                &sB[buf][((wn * 64 + ni * 16 + lr) * BK + lkb) ^ sw]);
#pragma unroll
        for (int mi = 0; mi < 4; ++mi)
#pragma unroll
            for (int ni = 0; ni < 4; ++ni)
                acc[mi][ni] = __builtin_amdgcn_mfma_f32_16x16x32_bf16(
                    af[mi], bfr[ni], acc[mi][ni], 0, 0, 0);
    };

    const int nt = K / BK;                 // 32 or 64
    // prologue: tiles 0,1,2 in flight (12 loads)
    stage(0, 0);
    stage(1, 1);
    stage(2, 2);

    for (int ts = 0; ts < nt - 3; ++ts) {
        WAITVM(8);               // tile ts landed; ts+1, ts+2 still flying
        BAR();
        SCHEDB();
        compute(ts % 3);         // frags consumed into regs before next BAR
        SCHEDB();
        BAR();
        stage(ts + 3, ts % 3);   // restage; vmcnt never drains to 0 in loop
    }
    WAITVM(8); BAR(); SCHEDB(); compute((nt - 3) % 3);
    WAITVM(4); BAR(); SCHEDB(); compute((nt - 2) % 3);
    WAITVM(0); BAR(); SCHEDB(); compute((nt - 1) % 3);

    // epilogue: C mapping col=lane&15, row=(lane>>4)*4+j
    float esum = 0.0f;
    const int prow = (lane >> 4) * 4;
#pragma unroll
    for (int mi = 0; mi < 4; ++mi) {
#pragma unroll
        for (int ni = 0; ni < 4; ++ni) {
            const int col = n0 + wn * 64 + ni * 16 + lr;
#pragma unroll
            for (int j = 0; j < 4; ++j) {
                const int row = m0 + wm * 64 + mi * 16 + prow + j;
                const float v = acc[mi][ni][j];
                if (role == 1) {
                    const float z  = v + bias_g[col];
                    const float xp = 1.0f / (1.0f + __expf(-z));
                    const float e  = xin[(int64_t)row * DIN + col] - xp;
                    exout[(int64_t)row * DIN + col] = (bf16_t)e;
                    esum += e * e;
                } else if (role == 2) {
                    const int64_t idx = (int64_t)row * HID + col;
                    const float nh = hf[idx] + LR * v;
                    hf[idx] = nh;
                    hb[idx] = (bf16_t)nh;
                } else {
                    if (col < DOUT) {
                        const int64_t idx = (int64_t)row * DOUT + col;
                        const float yp = v + bias_o[col];
                        const float yo = yout[idx];
                        const float e  = yo - yp;
                        yout[idx] = yo + LR * e;
                        esum += e * e;
                    }
                }
            }
        }
    }
    if constexpr (EPI != 2) {
#pragma unroll
        for (int off = 32; off; off >>= 1) esum += __shfl_down(esum, off, 64);
        if (lane == 0) red[wave] = esum;
        __syncthreads();
        if (t == 0)
            atomicAdd(energy, red[0] + red[1] + red[2] + red[3]);
    }
}

// W_rec [HID][DIN] f32 -> bf16 copy + bf16 transpose [DIN][HID]
__global__ void conv_wrec(const float* __restrict__ W, bf16_t* __restrict__ Wb,
                          bf16_t* __restrict__ WbT)
{
    __shared__ float tile[32][33];
    const int tx = threadIdx.x & 31;
    const int ty = threadIdx.x >> 5; // 0..7
    const int c0 = blockIdx.x * 32;  // DIN
    const int r0 = blockIdx.y * 32;  // HID
#pragma unroll
    for (int rr = ty; rr < 32; rr += 8) {
        const float v = W[(int64_t)(r0 + rr) * DIN + c0 + tx];
        Wb[(int64_t)(r0 + rr) * DIN + c0 + tx] = (bf16_t)v;
        tile[rr][tx] = v;
    }
    __syncthreads();
#pragma unroll
    for (int rr = ty; rr < 32; rr += 8)
        WbT[(int64_t)(c0 + rr) * HID + r0 + tx] = (bf16_t)tile[tx][rr];
}

// W_out [DOUT][HID] f32 -> bf16 [1024][HID], rows >= DOUT zero-padded
__global__ void conv_wout(const float* __restrict__ W, bf16_t* __restrict__ Wb)
{
    const int i = blockIdx.x * 256 + threadIdx.x; // over 1024*2048
    const int r = i >> 11;
    const int c = i & 2047;
    Wb[i] = (r < DOUT) ? (bf16_t)W[(int64_t)r * HID + c] : (bf16_t)0.0f;
}

// iteration 0: h = 0 -> x_pred = 0.5 exactly; e_x = x - 0.5 (+ energy)
__global__ void ex0_kernel(const float* __restrict__ x, bf16_t* __restrict__ ex,
                           float* __restrict__ energy)
{
    __shared__ float red[4];
    const int t = threadIdx.x, lane = t & 63, wave = t >> 6;
    const int i = (blockIdx.x * 256 + t) * 4;
    const float4 v = *reinterpret_cast<const float4*>(&x[i]);
    const float e0 = v.x - 0.5f, e1 = v.y - 0.5f, e2 = v.z - 0.5f, e3 = v.w - 0.5f;
    bf16x4 o = {(bf16_t)e0, (bf16_t)e1, (bf16_t)e2, (bf16_t)e3};
    *reinterpret_cast<bf16x4*>(&ex[i]) = o;
    float esum = e0 * e0 + e1 * e1 + e2 * e2 + e3 * e3;
#pragma unroll
    for (int off = 32; off; off >>= 1) esum += __shfl_down(esum, off, 64);
    if (lane == 0) red[wave] = esum;
    __syncthreads();
    if (t == 0) atomicAdd(energy, red[0] + red[1] + red[2] + red[3]);
}

__global__ void finalize_kernel(const float* __restrict__ energy,
                                float* __restrict__ out)
{
    out[0] = energy[0] * (1.0f / ((float)BATCH * (float)NITER));
}

extern "C" void kernel_launch(void* const* d_in, const int* in_sizes, int n_in,
                              void* d_out, int out_size, void* d_ws, size_t ws_size,
                              hipStream_t stream)
{
    (void)in_sizes; (void)n_in; (void)out_size; (void)ws_size;
    const float* x        = (const float*)d_in[0];
    const float* W_rec    = (const float*)d_in[1];
    const float* W_out    = (const float*)d_in[2];
    const float* bias_out = (const float*)d_in[3];
    const float* bias_gen = (const float*)d_in[4];
    float* y = (float*)d_out; // [BATCH*DOUT] then [1] energy

    char* ws = (char*)d_ws;
    size_t off = 0;
    float* h_f32 = (float*)(ws + off);   off += (size_t)BATCH * HID * 4;  // 32 MB
    bf16_t* h_bf = (bf16_t*)(ws + off);  off += (size_t)BATCH * HID * 2;  // 16 MB
    bf16_t* ex_bf = (bf16_t*)(ws + off); off += (size_t)BATCH * DIN * 2;  //  8 MB
    bf16_t* wrec_bf = (bf16_t*)(ws + off);  off += (size_t)HID * DIN * 2; //  4 MB
    bf16_t* wrecT_bf = (bf16_t*)(ws + off); off += (size_t)HID * DIN * 2; //  4 MB
    bf16_t* wout_bf = (bf16_t*)(ws + off);  off += (size_t)1024 * HID * 2;//  4 MB
    float* energy = (float*)(ws + off);     off += 256;

    hipMemsetAsync(h_f32, 0, (size_t)BATCH * HID * 4, stream);
    hipMemsetAsync(y, 0, (size_t)BATCH * DOUT * 4, stream);
    hipMemsetAsync(energy, 0, 4, stream);

    conv_wrec<<<dim3(DIN / 32, HID / 32), 256, 0, stream>>>(W_rec, wrec_bf, wrecT_bf);
    conv_wout<<<(1024 * HID) / 256, 256, 0, stream>>>(W_out, wout_bf);

    const dim3 g2(BATCH / BM, HID / BN);    // 32 x 16  (h-update, K=DIN)
    const dim3 g13(BATCH / BM, 16);         // 32 x 16  (merged y-update + next e_x)
    const dim3 g3(BATCH / BM, 1024 / BN);   // 32 x 8   (final y-update)

    // iteration 0 e_x (h = 0 -> x_pred = 0.5 exactly)
    ex0_kernel<<<(BATCH * DIN) / 1024, 256, 0, stream>>>(x, ex_bf, energy);

    for (int it = 0; it < NITER; ++it) {
        gemm_bt<2><<<g2, 256, 0, stream>>>(ex_bf, wrec_bf, nullptr, DIN,
                                           nullptr, nullptr, nullptr,
                                           nullptr, h_f32, h_bf, nullptr, nullptr);
        if (it < NITER - 1)
            gemm_bt<13><<<g13, 256, 0, stream>>>(h_bf, wrecT_bf, wout_bf, HID,
                                                 x, bias_gen, bias_out,
                                                 ex_bf, nullptr, nullptr, y, energy);
        else
            gemm_bt<3><<<g3, 256, 0, stream>>>(h_bf, wout_bf, nullptr, HID,
                                               nullptr, nullptr, bias_out,
                                               nullptr, nullptr, nullptr, y, energy);
    }
    finalize_kernel<<<1, 1, 0, stream>>>(energy, y + (size_t)BATCH * DOUT);
}

// Round 6
// 4083.389 us; speedup vs baseline: 1.4354x; 1.4354x over previous
//
#include <hip/hip_runtime.h>
#include <hip/hip_bf16.h>
#include <cstdint>

typedef __bf16 bf16_t;
typedef __bf16 bf16x4 __attribute__((ext_vector_type(4)));
typedef __bf16 bf16x8 __attribute__((ext_vector_type(8)));
typedef float f32x4 __attribute__((ext_vector_type(4)));

#define BATCH 4096
#define DIN   1024
#define HID   2048
#define DOUT  1000
#define NITER 50
#define LR    0.001f

#define BM 128
#define BN 128
#define BK 32
#define NBUF 4

// async global -> LDS, 16 B per lane. LDS dest is wave-uniform base + lane*16.
#define GLDS(g, l)                                                        \
    __builtin_amdgcn_global_load_lds(                                     \
        (const __attribute__((address_space(1))) void*)(g),               \
        (__attribute__((address_space(3))) void*)(l), 16, 0, 0)

#define WAITVM(N) asm volatile("s_waitcnt vmcnt(" #N ")" ::: "memory")
#define BAR()     __builtin_amdgcn_s_barrier()
#define SCHEDB()  __builtin_amdgcn_sched_barrier(0)

// ---------------------------------------------------------------------------
// gemm_bt: C[M,N] = A[M,K] @ Bt[N,K]^T, row-major, bf16 in, f32 acc.
// 512 threads = 8 waves (2x4); wave tile 64x32 -> acc[4][2]  (R4 structure).
// K-loop: 4 LDS buffers, TWO K-tiles per barrier pair (halves barrier count
// vs R4), counted vmcnt (T4): steady state 2 tiles (4 loads/thread) in
// flight across barriers; vmcnt 4 -> 8 in loop, 4 -> 0 tail.  No LDS swizzle:
// R5 falsified the read-conflict theory (SQ_LDS_BANK_CONFLICT is GLDS-write
// dominated; swizzle only broke offset folding).
// EPI: 2  = h-update (B1 = W_rec)
//      3  = y-update (B1 = W_out padded)
//      13 = merged: blockIdx.y<8 -> role 3 (B2=W_out), else role 1 (B1=W_rec^T)
// role 1: e_x = x - sigmoid(z + bias_gen); store bf16; energy += e^2
// role 2: h_f32 += LR*z; h_bf16 = (bf16)h_f32
// role 3: cols<DOUT: e = y - (z + bias_out); y += LR*e; energy += e^2
// ---------------------------------------------------------------------------
template <int EPI>
__global__ __launch_bounds__(512) void gemm_bt(
    const bf16_t* __restrict__ A, const bf16_t* __restrict__ B1,
    const bf16_t* __restrict__ B2, int K,
    const float* __restrict__ xin, const float* __restrict__ bias_g,
    const float* __restrict__ bias_o,
    bf16_t* __restrict__ exout, float* __restrict__ hf, bf16_t* __restrict__ hb,
    float* __restrict__ yout, float* __restrict__ energy)
{
    __shared__ __align__(16) bf16_t sA[NBUF][BM * BK];
    __shared__ __align__(16) bf16_t sB[NBUF][BN * BK];
    __shared__ float red[8];

    const int t    = threadIdx.x;
    const int lane = t & 63;
    const int wave = t >> 6;        // 0..7
    const int wm   = wave >> 2;     // wave row (0..1) -> 64 rows
    const int wn   = wave & 3;      // wave col (0..3) -> 32 cols
    const int m0   = blockIdx.x * BM;
    const int lr   = lane & 15;        // fragment row/col within 16
    const int lkb  = (lane >> 4) * 8;  // fragment k offset (8 contiguous)

    int role = EPI;
    int n0   = blockIdx.y * BN;
    const bf16_t* Bt = B1;
    if constexpr (EPI == 13) {
        if ((int)blockIdx.y < 8) {            // role 3: W_out cols 0..1023
            role = 3; Bt = B2;
        } else {                              // role 1: W_rec^T cols 0..1023
            role = 1; Bt = B1; n0 = ((int)blockIdx.y - 8) * BN;
        }
    }

    f32x4 acc[4][2] = {};

    // staging: lane l of wave w -> tile row w*16 + l/4, col chunk (l&3)*8
    const int srow = wave * 16 + (lane >> 2);
    const int scol = (lane & 3) * 8;
    const bf16_t* gA = A  + (int64_t)(m0 + srow) * K + scol;
    const bf16_t* gB = Bt + (int64_t)(n0 + srow) * K + scol;

    auto stage = [&](int tile, int buf) {
        const int64_t ko = (int64_t)tile * BK;
        GLDS(gA + ko, &sA[buf][wave * 512]);
        GLDS(gB + ko, &sB[buf][wave * 512]);
    };

    auto compute = [&](int buf) {
        bf16x8 af[4], bfr[2];
#pragma unroll
        for (int mi = 0; mi < 4; ++mi)
            af[mi] = *reinterpret_cast<const bf16x8*>(
                &sA[buf][(wm * 64 + mi * 16 + lr) * BK + lkb]);
#pragma unroll
        for (int ni = 0; ni < 2; ++ni)
            bfr[ni] = *reinterpret_cast<const bf16x8*>(
                &sB[buf][(wn * 32 + ni * 16 + lr) * BK + lkb]);
#pragma unroll
        for (int mi = 0; mi < 4; ++mi)
#pragma unroll
            for (int ni = 0; ni < 2; ++ni)
                acc[mi][ni] = __builtin_amdgcn_mfma_f32_16x16x32_bf16(
                    af[mi], bfr[ni], acc[mi][ni], 0, 0, 0);
    };

    const int npairs = (K / BK) / 2;       // 16 or 32
    // prologue: tiles 0..3 in flight (8 loads/thread)
    stage(0, 0); stage(1, 1); stage(2, 2); stage(3, 3);

    for (int p = 0; p < npairs - 2; ++p) {
        const int t0 = 2 * p;
        WAITVM(4);               // pair p landed; pair p+1 (4 loads) flying
        BAR();
        SCHEDB();
        compute(t0 & 3);
        compute((t0 + 1) & 3);
        BAR();                   // all waves done with bufs t0, t0+1
        stage(t0 + 4, t0 & 3);   // restage; vmcnt back to 8, never 0 in loop
        stage(t0 + 5, (t0 + 1) & 3);
    }
    {
        const int t0 = 2 * npairs - 4;
        WAITVM(4); BAR(); SCHEDB();
        compute(t0 & 3); compute((t0 + 1) & 3);
    }
    {
        const int t0 = 2 * npairs - 2;
        WAITVM(0); BAR(); SCHEDB();
        compute(t0 & 3); compute((t0 + 1) & 3);
    }

    // epilogue: C mapping col=lane&15, row=(lane>>4)*4+j
    float esum = 0.0f;
    const int prow = (lane >> 4) * 4;
#pragma unroll
    for (int mi = 0; mi < 4; ++mi) {
#pragma unroll
        for (int ni = 0; ni < 2; ++ni) {
            const int col = n0 + wn * 32 + ni * 16 + lr;
#pragma unroll
            for (int j = 0; j < 4; ++j) {
                const int row = m0 + wm * 64 + mi * 16 + prow + j;
                const float v = acc[mi][ni][j];
                if (role == 1) {
                    const float z  = v + bias_g[col];
                    const float xp = 1.0f / (1.0f + __expf(-z));
                    const float e  = xin[(int64_t)row * DIN + col] - xp;
                    exout[(int64_t)row * DIN + col] = (bf16_t)e;
                    esum += e * e;
                } else if (role == 2) {
                    const int64_t idx = (int64_t)row * HID + col;
                    const float nh = hf[idx] + LR * v;
                    hf[idx] = nh;
                    hb[idx] = (bf16_t)nh;
                } else {
                    if (col < DOUT) {
                        const int64_t idx = (int64_t)row * DOUT + col;
                        const float yp = v + bias_o[col];
                        const float yo = yout[idx];
                        const float e  = yo - yp;
                        yout[idx] = yo + LR * e;
                        esum += e * e;
                    }
                }
            }
        }
    }
    if constexpr (EPI != 2) {
#pragma unroll
        for (int off = 32; off; off >>= 1) esum += __shfl_down(esum, off, 64);
        if (lane == 0) red[wave] = esum;
        __syncthreads();
        if (t == 0) {
            float s = 0.0f;
#pragma unroll
            for (int w = 0; w < 8; ++w) s += red[w];
            atomicAdd(energy, s);
        }
    }
}

// W_rec [HID][DIN] f32 -> bf16 copy + bf16 transpose [DIN][HID]
__global__ void conv_wrec(const float* __restrict__ W, bf16_t* __restrict__ Wb,
                          bf16_t* __restrict__ WbT)
{
    __shared__ float tile[32][33];
    const int tx = threadIdx.x & 31;
    const int ty = threadIdx.x >> 5; // 0..7
    const int c0 = blockIdx.x * 32;  // DIN
    const int r0 = blockIdx.y * 32;  // HID
#pragma unroll
    for (int rr = ty; rr < 32; rr += 8) {
        const float v = W[(int64_t)(r0 + rr) * DIN + c0 + tx];
        Wb[(int64_t)(r0 + rr) * DIN + c0 + tx] = (bf16_t)v;
        tile[rr][tx] = v;
    }
    __syncthreads();
#pragma unroll
    for (int rr = ty; rr < 32; rr += 8)
        WbT[(int64_t)(c0 + rr) * HID + r0 + tx] = (bf16_t)tile[tx][rr];
}

// W_out [DOUT][HID] f32 -> bf16 [1024][HID], rows >= DOUT zero-padded
__global__ void conv_wout(const float* __restrict__ W, bf16_t* __restrict__ Wb)
{
    const int i = blockIdx.x * 256 + threadIdx.x; // over 1024*2048
    const int r = i >> 11;
    const int c = i & 2047;
    Wb[i] = (r < DOUT) ? (bf16_t)W[(int64_t)r * HID + c] : (bf16_t)0.0f;
}

// iteration 0: h = 0 -> x_pred = 0.5 exactly; e_x = x - 0.5 (+ energy)
__global__ void ex0_kernel(const float* __restrict__ x, bf16_t* __restrict__ ex,
                           float* __restrict__ energy)
{
    __shared__ float red[4];
    const int t = threadIdx.x, lane = t & 63, wave = t >> 6;
    const int i = (blockIdx.x * 256 + t) * 4;
    const float4 v = *reinterpret_cast<const float4*>(&x[i]);
    const float e0 = v.x - 0.5f, e1 = v.y - 0.5f, e2 = v.z - 0.5f, e3 = v.w - 0.5f;
    bf16x4 o = {(bf16_t)e0, (bf16_t)e1, (bf16_t)e2, (bf16_t)e3};
    *reinterpret_cast<bf16x4*>(&ex[i]) = o;
    float esum = e0 * e0 + e1 * e1 + e2 * e2 + e3 * e3;
#pragma unroll
    for (int off = 32; off; off >>= 1) esum += __shfl_down(esum, off, 64);
    if (lane == 0) red[wave] = esum;
    __syncthreads();
    if (t == 0) atomicAdd(energy, red[0] + red[1] + red[2] + red[3]);
}

__global__ void finalize_kernel(const float* __restrict__ energy,
                                float* __restrict__ out)
{
    out[0] = energy[0] * (1.0f / ((float)BATCH * (float)NITER));
}

extern "C" void kernel_launch(void* const* d_in, const int* in_sizes, int n_in,
                              void* d_out, int out_size, void* d_ws, size_t ws_size,
                              hipStream_t stream)
{
    (void)in_sizes; (void)n_in; (void)out_size; (void)ws_size;
    const float* x        = (const float*)d_in[0];
    const float* W_rec    = (const float*)d_in[1];
    const float* W_out    = (const float*)d_in[2];
    const float* bias_out = (const float*)d_in[3];
    const float* bias_gen = (const float*)d_in[4];
    float* y = (float*)d_out; // [BATCH*DOUT] then [1] energy

    char* ws = (char*)d_ws;
    size_t off = 0;
    float* h_f32 = (float*)(ws + off);   off += (size_t)BATCH * HID * 4;  // 32 MB
    bf16_t* h_bf = (bf16_t*)(ws + off);  off += (size_t)BATCH * HID * 2;  // 16 MB
    bf16_t* ex_bf = (bf16_t*)(ws + off); off += (size_t)BATCH * DIN * 2;  //  8 MB
    bf16_t* wrec_bf = (bf16_t*)(ws + off);  off += (size_t)HID * DIN * 2; //  4 MB
    bf16_t* wrecT_bf = (bf16_t*)(ws + off); off += (size_t)HID * DIN * 2; //  4 MB
    bf16_t* wout_bf = (bf16_t*)(ws + off);  off += (size_t)1024 * HID * 2;//  4 MB
    float* energy = (float*)(ws + off);     off += 256;

    hipMemsetAsync(h_f32, 0, (size_t)BATCH * HID * 4, stream);
    hipMemsetAsync(y, 0, (size_t)BATCH * DOUT * 4, stream);
    hipMemsetAsync(energy, 0, 4, stream);

    conv_wrec<<<dim3(DIN / 32, HID / 32), 256, 0, stream>>>(W_rec, wrec_bf, wrecT_bf);
    conv_wout<<<(1024 * HID) / 256, 256, 0, stream>>>(W_out, wout_bf);

    const dim3 g2(BATCH / BM, HID / BN);    // 32 x 16  (h-update, K=DIN)
    const dim3 g13(BATCH / BM, 16);         // 32 x 16  (merged y-update + next e_x)
    const dim3 g3(BATCH / BM, 1024 / BN);   // 32 x 8   (final y-update)

    // iteration 0 e_x (h = 0 -> x_pred = 0.5 exactly)
    ex0_kernel<<<(BATCH * DIN) / 1024, 256, 0, stream>>>(x, ex_bf, energy);

    for (int it = 0; it < NITER; ++it) {
        gemm_bt<2><<<g2, 512, 0, stream>>>(ex_bf, wrec_bf, nullptr, DIN,
                                           nullptr, nullptr, nullptr,
                                           nullptr, h_f32, h_bf, nullptr, nullptr);
        if (it < NITER - 1)
            gemm_bt<13><<<g13, 512, 0, stream>>>(h_bf, wrecT_bf, wout_bf, HID,
                                                 x, bias_gen, bias_out,
                                                 ex_bf, nullptr, nullptr, y, energy);
        else
            gemm_bt<3><<<g3, 512, 0, stream>>>(h_bf, wout_bf, nullptr, HID,
                                               nullptr, nullptr, bias_out,
                                               nullptr, nullptr, nullptr, y, energy);
    }
    finalize_kernel<<<1, 1, 0, stream>>>(energy, y + (size_t)BATCH * DOUT);
}

// Round 7
// 2020.414 us; speedup vs baseline: 2.9011x; 2.0211x over previous
//
#include <hip/hip_runtime.h>
#include <hip/hip_bf16.h>
#include <cstdint>

typedef __bf16 bf16_t;
typedef __bf16 bf16x4 __attribute__((ext_vector_type(4)));
typedef __bf16 bf16x8 __attribute__((ext_vector_type(8)));
typedef float f32x4 __attribute__((ext_vector_type(4)));

#define BATCH 4096
#define DIN   1024
#define HID   2048
#define DOUT  1000
#define NITER 50
#define LR    0.001f

#define BM 128
#define BN 128
#define BK 32
#define NBUF 4

// async global -> LDS, 16 B per lane. LDS dest is wave-uniform base + lane*16.
#define GLDS(g, l)                                                        \
    __builtin_amdgcn_global_load_lds(                                     \
        (const __attribute__((address_space(1))) void*)(g),               \
        (__attribute__((address_space(3))) void*)(l), 16, 0, 0)

#define WAITVM(N) asm volatile("s_waitcnt vmcnt(" #N ")" ::: "memory")
#define BAR()     __builtin_amdgcn_s_barrier()
#define SCHEDB()  __builtin_amdgcn_sched_barrier(0)

// ---------------------------------------------------------------------------
// Reformulated predictive-coding step (h eliminated):
//   u := h W_rec + b_gen   ->  u += LR * (e_x @ Wg),  Wg = W_rec^T W_rec (sym)
//   z := h W_out^T + b_out ->  z += LR * (e_x @ Wc^T), Wc = W_out W_rec
//   e_x' = x - sigmoid(u)      (fused in U epilogue)
//   e_y' = (1+LR) e_y - D      (fused in Z epilogue; D = LR e_x Wc^T)
//   y_final = (1+LR) e_y + z   (MODE 2)
// One GEMM dispatch per iteration: A = e_x (bf16, ping-pong), K = 1024,
// grid 32x16: blockIdx.y<8 -> U role (Bt=Wg), >=8 -> Z role (Bt=Wc).
//
// GEMM core = R6-proven: 512 thr / 8 waves (2x4), wave tile 64x32 acc[4][2],
// 4 LDS buffers, two K-tiles per barrier pair, counted vmcnt (T4).
//
// MODE: 0 = UZ (1<=i<=48), 1 = UZ first (i=0: u/z seeded from biases),
//       2 = Z-only final (i=49: writes y), 3 = setup (Wg | Wc), K=2048.
// ---------------------------------------------------------------------------
template <int MODE>
__global__ __launch_bounds__(512) void pc_gemm(
    const bf16_t* __restrict__ Aex, bf16_t* __restrict__ wrecT,
    bf16_t* __restrict__ woutP, bf16_t* __restrict__ wg,
    bf16_t* __restrict__ wc,
    const float* __restrict__ xin, const float* __restrict__ bias_g,
    const float* __restrict__ bias_o,
    bf16_t* __restrict__ exnext, float* __restrict__ u,
    float* __restrict__ z, bf16_t* __restrict__ ey,
    float* __restrict__ yout, float* __restrict__ energy)
{
    __shared__ __align__(16) bf16_t sA[NBUF][BM * BK];
    __shared__ __align__(16) bf16_t sB[NBUF][BN * BK];
    __shared__ float red[8];

    const int t    = threadIdx.x;
    const int lane = t & 63;
    const int wave = t >> 6;        // 0..7
    const int wm   = wave >> 2;     // wave row (0..1) -> 64 rows
    const int wn   = wave & 3;      // wave col (0..3) -> 32 cols
    const int m0   = blockIdx.x * BM;
    const int lr   = lane & 15;
    const int lkb  = (lane >> 4) * 8;

    int role, n0, K;
    const bf16_t *Aop, *Bop;
    if constexpr (MODE == 3) {
        role = (int)blockIdx.y >= 8; n0 = ((int)blockIdx.y & 7) * BN; K = HID;
        Aop = role ? woutP : wrecT;  Bop = wrecT;
    } else if constexpr (MODE == 2) {
        role = 1; n0 = (int)blockIdx.y * BN; K = DIN;
        Aop = Aex; Bop = wc;
    } else {
        role = (int)blockIdx.y >= 8; n0 = ((int)blockIdx.y & 7) * BN; K = DIN;
        Aop = Aex; Bop = role ? wc : wg;
    }

    f32x4 acc[4][2] = {};

    // staging: lane l of wave w -> tile row w*16 + l/4, col chunk (l&3)*8
    const int srow = wave * 16 + (lane >> 2);
    const int scol = (lane & 3) * 8;
    const bf16_t* gA = Aop + (int64_t)(m0 + srow) * K + scol;
    const bf16_t* gB = Bop + (int64_t)(n0 + srow) * K + scol;

    auto stage = [&](int tile, int buf) {
        const int64_t ko = (int64_t)tile * BK;
        GLDS(gA + ko, &sA[buf][wave * 512]);
        GLDS(gB + ko, &sB[buf][wave * 512]);
    };

    auto compute = [&](int buf) {
        bf16x8 af[4], bfr[2];
#pragma unroll
        for (int mi = 0; mi < 4; ++mi)
            af[mi] = *reinterpret_cast<const bf16x8*>(
                &sA[buf][(wm * 64 + mi * 16 + lr) * BK + lkb]);
#pragma unroll
        for (int ni = 0; ni < 2; ++ni)
            bfr[ni] = *reinterpret_cast<const bf16x8*>(
                &sB[buf][(wn * 32 + ni * 16 + lr) * BK + lkb]);
#pragma unroll
        for (int mi = 0; mi < 4; ++mi)
#pragma unroll
            for (int ni = 0; ni < 2; ++ni)
                acc[mi][ni] = __builtin_amdgcn_mfma_f32_16x16x32_bf16(
                    af[mi], bfr[ni], acc[mi][ni], 0, 0, 0);
    };

    const int npairs = (K / BK) / 2;       // 16 (UZ) or 32 (setup)
    stage(0, 0); stage(1, 1); stage(2, 2); stage(3, 3);

    for (int p = 0; p < npairs - 2; ++p) {
        const int t0 = 2 * p;
        WAITVM(4);               // pair p landed; pair p+1 still flying
        BAR();
        SCHEDB();
        compute(t0 & 3);
        compute((t0 + 1) & 3);
        BAR();
        stage(t0 + 4, t0 & 3);   // vmcnt never drains to 0 in loop
        stage(t0 + 5, (t0 + 1) & 3);
    }
    {
        const int t0 = 2 * npairs - 4;
        WAITVM(4); BAR(); SCHEDB();
        compute(t0 & 3); compute((t0 + 1) & 3);
    }
    {
        const int t0 = 2 * npairs - 2;
        WAITVM(0); BAR(); SCHEDB();
        compute(t0 & 3); compute((t0 + 1) & 3);
    }

    // epilogue: C mapping col=lane&15, row=(lane>>4)*4+j
    float esum = 0.0f;
    const int prow = (lane >> 4) * 4;
#pragma unroll
    for (int mi = 0; mi < 4; ++mi) {
#pragma unroll
        for (int ni = 0; ni < 2; ++ni) {
            const int col = n0 + wn * 32 + ni * 16 + lr;
#pragma unroll
            for (int j = 0; j < 4; ++j) {
                const int row = m0 + wm * 64 + mi * 16 + prow + j;
                const float v = acc[mi][ni][j];
                if constexpr (MODE == 3) {
                    bf16_t* cout = role ? wc : wg;
                    cout[(int64_t)row * 1024 + col] = (bf16_t)v;
                } else {
                    if (role == 0) {
                        // U role: u += LR*D; e_x' = x - sigmoid(u); energy
                        const int64_t idx = (int64_t)row * DIN + col;
                        const float D  = LR * v;
                        const float un = (MODE == 1 ? bias_g[col] : u[idx]) + D;
                        u[idx] = un;
                        const float xp = 1.0f / (1.0f + __expf(-un));
                        const float e  = xin[idx] - xp;
                        exnext[idx] = (bf16_t)e;
                        esum += e * e;
                    } else if (col < DOUT) {
                        // Z role: z += D; e_y = (1+LR)e_y - D; energy
                        const int64_t idx = (int64_t)row * 1024 + col;
                        const float D  = LR * v;
                        const float zn = (MODE == 1 ? bias_o[col] : z[idx]) + D;
                        const float eyn = (MODE == 1)
                            ? -zn
                            : (1.0f + LR) * (float)ey[idx] - D;
                        if constexpr (MODE == 2) {
                            yout[(int64_t)row * DOUT + col] =
                                (1.0f + LR) * eyn + zn;
                        } else {
                            z[idx]  = zn;
                            ey[idx] = (bf16_t)eyn;
                        }
                        esum += eyn * eyn;
                    }
                }
            }
        }
    }
    if constexpr (MODE != 3) {
#pragma unroll
        for (int off = 32; off; off >>= 1) esum += __shfl_down(esum, off, 64);
        if (lane == 0) red[wave] = esum;
        __syncthreads();
        if (t == 0) {
            float s = 0.0f;
#pragma unroll
            for (int w = 0; w < 8; ++w) s += red[w];
            atomicAdd(energy, s);
        }
    }
}

// W_rec [HID][DIN] f32 -> bf16 transpose [DIN][HID]
__global__ void conv_wrec(const float* __restrict__ W, bf16_t* __restrict__ WbT)
{
    __shared__ float tile[32][33];
    const int tx = threadIdx.x & 31;
    const int ty = threadIdx.x >> 5; // 0..7
    const int c0 = blockIdx.x * 32;  // DIN
    const int r0 = blockIdx.y * 32;  // HID
#pragma unroll
    for (int rr = ty; rr < 32; rr += 8)
        tile[rr][tx] = W[(int64_t)(r0 + rr) * DIN + c0 + tx];
    __syncthreads();
#pragma unroll
    for (int rr = ty; rr < 32; rr += 8)
        WbT[(int64_t)(c0 + rr) * HID + r0 + tx] = (bf16_t)tile[tx][rr];
}

// W_out [DOUT][HID] f32 -> bf16 [1024][HID], rows >= DOUT zero-padded
__global__ void conv_wout(const float* __restrict__ W, bf16_t* __restrict__ Wb)
{
    const int i = blockIdx.x * 256 + threadIdx.x; // over 1024*2048
    const int r = i >> 11;
    const int c = i & 2047;
    Wb[i] = (r < DOUT) ? (bf16_t)W[(int64_t)r * HID + c] : (bf16_t)0.0f;
}

// iteration 0: e_x0 = x - sigmoid(b_gen), + energy
__global__ void ex0_kernel(const float* __restrict__ x,
                           const float* __restrict__ bias_g,
                           bf16_t* __restrict__ ex, float* __restrict__ energy)
{
    __shared__ float red[4];
    const int t = threadIdx.x, lane = t & 63, wave = t >> 6;
    const int i = (blockIdx.x * 256 + t) * 4;
    const int c0 = i & (DIN - 1);
    const float4 v = *reinterpret_cast<const float4*>(&x[i]);
    float e[4];
    const float b0 = bias_g[c0], b1 = bias_g[c0 + 1],
                b2 = bias_g[c0 + 2], b3 = bias_g[c0 + 3];
    e[0] = v.x - 1.0f / (1.0f + __expf(-b0));
    e[1] = v.y - 1.0f / (1.0f + __expf(-b1));
    e[2] = v.z - 1.0f / (1.0f + __expf(-b2));
    e[3] = v.w - 1.0f / (1.0f + __expf(-b3));
    bf16x4 o = {(bf16_t)e[0], (bf16_t)e[1], (bf16_t)e[2], (bf16_t)e[3]};
    *reinterpret_cast<bf16x4*>(&ex[i]) = o;
    float esum = e[0]*e[0] + e[1]*e[1] + e[2]*e[2] + e[3]*e[3];
#pragma unroll
    for (int off = 32; off; off >>= 1) esum += __shfl_down(esum, off, 64);
    if (lane == 0) red[wave] = esum;
    __syncthreads();
    if (t == 0) atomicAdd(energy, red[0] + red[1] + red[2] + red[3]);
}

__global__ void finalize_kernel(const float* __restrict__ energy,
                                float* __restrict__ out)
{
    out[0] = energy[0] * (1.0f / ((float)BATCH * (float)NITER));
}

extern "C" void kernel_launch(void* const* d_in, const int* in_sizes, int n_in,
                              void* d_out, int out_size, void* d_ws, size_t ws_size,
                              hipStream_t stream)
{
    (void)in_sizes; (void)n_in; (void)out_size; (void)ws_size;
    const float* x        = (const float*)d_in[0];
    const float* W_rec    = (const float*)d_in[1];
    const float* W_out    = (const float*)d_in[2];
    const float* bias_out = (const float*)d_in[3];
    const float* bias_gen = (const float*)d_in[4];
    float* y = (float*)d_out; // [BATCH*DOUT] then [1] energy

    char* ws = (char*)d_ws;
    size_t off = 0;
    float* u      = (float*)(ws + off);   off += (size_t)BATCH * DIN * 4;   // 16 MB
    float* z      = (float*)(ws + off);   off += (size_t)BATCH * 1024 * 4;  // 16 MB
    bf16_t* exA   = (bf16_t*)(ws + off);  off += (size_t)BATCH * DIN * 2;   //  8 MB
    bf16_t* exB   = (bf16_t*)(ws + off);  off += (size_t)BATCH * DIN * 2;   //  8 MB
    bf16_t* ey    = (bf16_t*)(ws + off);  off += (size_t)BATCH * 1024 * 2;  //  8 MB
    bf16_t* wrecT = (bf16_t*)(ws + off);  off += (size_t)DIN * HID * 2;     //  4 MB
    bf16_t* woutP = (bf16_t*)(ws + off);  off += (size_t)1024 * HID * 2;    //  4 MB
    bf16_t* wg    = (bf16_t*)(ws + off);  off += (size_t)1024 * 1024 * 2;   //  2 MB
    bf16_t* wc    = (bf16_t*)(ws + off);  off += (size_t)1024 * 1024 * 2;   //  2 MB
    float* energy = (float*)(ws + off);   off += 256;                       // 68 MB total

    hipMemsetAsync(energy, 0, 4, stream);

    conv_wrec<<<dim3(DIN / 32, HID / 32), 256, 0, stream>>>(W_rec, wrecT);
    conv_wout<<<(1024 * HID) / 256, 256, 0, stream>>>(W_out, woutP);
    // setup: Wg = W_rec^T W_rec (y<8), Wc = W_out W_rec (y>=8), K = 2048
    pc_gemm<3><<<dim3(8, 16), 512, 0, stream>>>(
        nullptr, wrecT, woutP, wg, wc, nullptr, nullptr, nullptr,
        nullptr, nullptr, nullptr, nullptr, nullptr, nullptr);

    ex0_kernel<<<(BATCH * DIN) / 1024, 256, 0, stream>>>(x, bias_gen, exA, energy);

    bf16_t* exbuf[2] = {exA, exB};
    for (int it = 0; it < NITER; ++it) {
        const bf16_t* src = exbuf[it & 1];
        bf16_t* dst = exbuf[(it & 1) ^ 1];
        if (it == 0)
            pc_gemm<1><<<dim3(BATCH / BM, 16), 512, 0, stream>>>(
                src, nullptr, nullptr, wg, wc, x, bias_gen, bias_out,
                dst, u, z, ey, nullptr, energy);
        else if (it < NITER - 1)
            pc_gemm<0><<<dim3(BATCH / BM, 16), 512, 0, stream>>>(
                src, nullptr, nullptr, wg, wc, x, bias_gen, bias_out,
                dst, u, z, ey, nullptr, energy);
        else
            pc_gemm<2><<<dim3(BATCH / BM, 8), 512, 0, stream>>>(
                src, nullptr, nullptr, wg, wc, x, bias_gen, bias_out,
                nullptr, u, z, ey, y, energy);
    }
    finalize_kernel<<<1, 1, 0, stream>>>(energy, y + (size_t)BATCH * DOUT);
}